// Round 21
// baseline (563.577 us; speedup 1.0000x reference)
//
#include <hip/hip_runtime.h>

// LSTMFeatureExtractor: 2-layer LSTM (H=128) over B=512, T=512, + a*relu(a) head.
// Round 21 = round-20 (best, 534us) + chain-latency trims only (no protocol
// changes): each gate's 4-deep hh-MFMA chain split into two 2-deep chains +
// final add (halves dependency depth on the serial path); S1's head MFMAs
// interleaved as an independent 5th chain. All r18/r19/r20 mechanics verbatim.

typedef _Float16 half8  __attribute__((ext_vector_type(8)));
typedef _Float16 half4_ __attribute__((ext_vector_type(4)));
typedef float    f32x4  __attribute__((ext_vector_type(4)));

#define H_    128
#define T_    512
#define B_    512
#define BCH   16
#define NBG   32
#define NCH   64                  // 8-step chunks
#define KPAD  136
#define RS    4                   // all ring depths
#define RH    4
#define SEEDSLOT (8 * 4 * 512 * 4)    // halves per (bg,slot): 65536 (128KB)
#define H0SLOT   (8 * 16 * 128)       // halves per (bg,slot): 16384 (32KB)

#define LOG2E 1.44269504089f

__device__ __forceinline__ float sigm_(float x) {
    return __builtin_amdgcn_rcpf(1.f + __builtin_amdgcn_exp2f(-LOG2E * x));
}
__device__ __forceinline__ float tanh_(float x) {
    return 1.f - 2.f * __builtin_amdgcn_rcpf(1.f + __builtin_amdgcn_exp2f((2.f * LOG2E) * x));
}
__device__ __forceinline__ void lds_barrier() {
    __builtin_amdgcn_sched_barrier(0);
    asm volatile("s_waitcnt lgkmcnt(0)" ::: "memory");
    __builtin_amdgcn_sched_barrier(0);
    __builtin_amdgcn_s_barrier();
    __builtin_amdgcn_sched_barrier(0);
}
__device__ __forceinline__ void fwait(const int* p, int tgt) {
    while (__hip_atomic_load(p, __ATOMIC_RELAXED, __HIP_MEMORY_SCOPE_AGENT) < tgt)
        __builtin_amdgcn_s_sleep(2);
}
__device__ __forceinline__ void frel(int* p, int v) {
    __hip_atomic_fetch_max(p, v, __ATOMIC_RELAXED, __HIP_MEMORY_SCOPE_AGENT);
}
__device__ __forceinline__ void st8(_Float16* p, half4_ v) {
    unsigned long long u;
    __builtin_memcpy(&u, &v, 8);
    __hip_atomic_store((unsigned long long*)p, u, __ATOMIC_RELAXED,
                       __HIP_MEMORY_SCOPE_AGENT);
}
__device__ __forceinline__ half4_ ld8(const _Float16* p) {
    unsigned long long u =
        __hip_atomic_load((const unsigned long long*)p, __ATOMIC_RELAXED,
                          __HIP_MEMORY_SCOPE_AGENT);
    half4_ v;
    __builtin_memcpy(&v, &u, 8);
    return v;
}
__device__ __forceinline__ f32x4 cvt4(half4_ h) {
    return f32x4{(float)h[0], (float)h[1], (float)h[2], (float)h[3]};
}
__device__ __forceinline__ half4_ cvh4(f32x4 v) {
    return half4_{(_Float16)v[0], (_Float16)v[1], (_Float16)v[2], (_Float16)v[3]};
}

#define MFMA16(A, Bv, C) __builtin_amdgcn_mfma_f32_16x16x32_f16((A), (Bv), (C), 0, 0, 0)

__global__ void __launch_bounds__(512)
lstm4(const float* __restrict__ y,
      const float* __restrict__ Wih0, const float* __restrict__ Whh0,
      const float* __restrict__ bih0, const float* __restrict__ bhh0,
      const float* __restrict__ Wih1, const float* __restrict__ Whh1,
      const float* __restrict__ bih1, const float* __restrict__ bhh1,
      const float* __restrict__ Wa,  const float* __restrict__ ba,
      _Float16* __restrict__ seeds0, _Float16* __restrict__ seeds1,
      _Float16* __restrict__ h0r,
      int* __restrict__ flags, float* __restrict__ out)
{
    __shared__ _Float16 xbuf[8][16][KPAD];   // P0/P1 staging
    __shared__ _Float16 hbuf[2][16][KPAD];   // S0/S1 h state

    const int tid = threadIdx.x;
    const int w   = tid >> 6;
    const int l   = tid & 63;
    const int g   = l >> 4;
    const int cl  = l & 15;
    const int role = blockIdx.x & 3;     // 0=P0 1=S0 2=P1 3=S1
    const int bg   = blockIdx.x >> 2;
    const int b0   = bg * BCH;

    int* fg0 = flags;         // P0 -> S0: seeds0 ready
    int* fs0 = flags + 32;    // S0 -> P0: seeds0 slot credit
    int* fh0 = flags + 64;    // S0 -> P1: h0 chunk ready
    int* fp1 = flags + 96;    // P1 -> S0: h0 slot credit (after staging)
    int* fg1 = flags + 128;   // P1 -> S1: seeds1 ready
    int* fs1 = flags + 160;   // S1 -> P1: seeds1 slot credit

    { // zero hbuf (initial h state for S roles)
        int* q = (int*)&hbuf[0][0][0];
        for (int i = tid; i < (int)(sizeof(hbuf) / 4); i += 512) q[i] = 0;
    }

    if (role == 0) {
        // ====================== P0: layer-0 input projection ======================
        half8 wf[4][4];
        #pragma unroll
        for (int gt = 0; gt < 4; ++gt) {
            const int grow = gt * 128 + w * 16 + cl;
            #pragma unroll
            for (int kt = 0; kt < 4; ++kt) {
                const float* pa = Wih0 + grow * H_ + kt * 32 + g * 8;
                f32x4 a0 = *(const f32x4*)(pa);
                f32x4 a1 = *(const f32x4*)(pa + 4);
                half8 fa;
                #pragma unroll
                for (int e = 0; e < 4; ++e) { fa[e] = (_Float16)a0[e]; fa[e + 4] = (_Float16)a1[e]; }
                wf[gt][kt] = fa;
            }
        }
        f32x4 bias[4];
        #pragma unroll
        for (int gt = 0; gt < 4; ++gt)
            #pragma unroll
            for (int r = 0; r < 4; ++r) {
                const int R = gt * 128 + w * 16 + g * 4 + r;
                bias[gt][r] = bih0[R] + bhh0[R];
            }
        __syncthreads();

        for (int c = 0; c < NCH; ++c) {
            if (tid == 0 && c >= RS) fwait(&fs0[bg], c - (RS - 1));
            __syncthreads();

            // stage y[b][k][c*8..+8) -> xbuf (f16)
            #pragma unroll
            for (int rr = 0; rr < 4; ++rr) {
                const int q = tid + rr * 512;
                const int b = q >> 7, k = q & 127;
                const float* src = y + ((size_t)((b0 + b) * H_ + k)) * T_ + c * 8;
                f32x4 v0 = *(const f32x4*)(src);
                f32x4 v1 = *(const f32x4*)(src + 4);
                #pragma unroll
                for (int e = 0; e < 4; ++e) {
                    xbuf[e][b][k]     = (_Float16)v0[e];
                    xbuf[e + 4][b][k] = (_Float16)v1[e];
                }
            }
            lds_barrier();

            _Float16* sb = seeds0 + (size_t)(bg * RS + (c & (RS - 1))) * SEEDSLOT;
            for (int s = 0; s < 8; ++s) {
                half8 xf[4];
                #pragma unroll
                for (int kt = 0; kt < 4; ++kt)
                    xf[kt] = *(const half8*)&xbuf[s][cl][kt * 32 + g * 8];
                #pragma unroll
                for (int gt = 0; gt < 4; ++gt) {
                    f32x4 acc = bias[gt];
                    #pragma unroll
                    for (int kt = 0; kt < 4; ++kt)
                        acc = MFMA16(wf[gt][kt], xf[kt], acc);
                    st8(sb + ((size_t)(s * 4 + gt) * 512 + tid) * 4, cvh4(acc));
                }
            }
            __syncthreads();                 // drains sc0sc1 stores (vmcnt)
            if (tid == 0) frel(&fg0[bg], c + 1);
        }
    } else if (role == 1) {
        // ====================== S0: light recurrence, layer 0 ======================
        half8 whh[4][4];
        #pragma unroll
        for (int gt = 0; gt < 4; ++gt) {
            const int grow = gt * 128 + w * 16 + cl;
            #pragma unroll
            for (int kt = 0; kt < 4; ++kt) {
                const float* pb = Whh0 + grow * H_ + kt * 32 + g * 8;
                f32x4 c0 = *(const f32x4*)(pb);
                f32x4 c1 = *(const f32x4*)(pb + 4);
                half8 fb;
                #pragma unroll
                for (int e = 0; e < 4; ++e) { fb[e] = (_Float16)c0[e]; fb[e + 4] = (_Float16)c1[e]; }
                whh[gt][kt] = fb;
            }
        }
        float cst[4] = {0.f, 0.f, 0.f, 0.f};
        half4_ sdn[2][4];
        __syncthreads();

        for (int c = 0; c < NCH; ++c) {
            const _Float16* sb = seeds0 + (size_t)(bg * RS + (c & (RS - 1))) * SEEDSLOT
                               + (size_t)tid * 4;
            _Float16* hb = h0r + (size_t)(bg * RH + (c & (RH - 1))) * H0SLOT;

            half4_ sd[2][4];
            if (c == 0) {
                if (tid == 0) fwait(&fg0[bg], 1);
                __syncthreads();
                #pragma unroll
                for (int gt = 0; gt < 4; ++gt)
                    sd[0][gt] = ld8(sb + (size_t)(0 * 4 + gt) * 2048);
                #pragma unroll
                for (int gt = 0; gt < 4; ++gt)
                    sd[1][gt] = ld8(sb + (size_t)(1 * 4 + gt) * 2048);
            } else {
                #pragma unroll
                for (int gt = 0; gt < 4; ++gt) { sd[0][gt] = sdn[0][gt]; sd[1][gt] = sdn[1][gt]; }
            }

            #pragma unroll
            for (int s = 0; s < 8; ++s) {
                const int rd = (s ^ 1) & 1;
                const int wr = s & 1;

                if (s == 6 && c + 1 < NCH) {    // cross-chunk seed prefetch
                    const _Float16* sbn = seeds0
                        + (size_t)(bg * RS + ((c + 1) & (RS - 1))) * SEEDSLOT
                        + (size_t)tid * 4;
                    #pragma unroll
                    for (int gt = 0; gt < 4; ++gt)
                        sdn[0][gt] = ld8(sbn + (size_t)(0 * 4 + gt) * 2048);
                    #pragma unroll
                    for (int gt = 0; gt < 4; ++gt)
                        sdn[1][gt] = ld8(sbn + (size_t)(1 * 4 + gt) * 2048);
                }

                half8 hf[4];
                #pragma unroll
                for (int kt = 0; kt < 4; ++kt)
                    hf[kt] = *(const half8*)&hbuf[rd][cl][kt * 32 + g * 8];

                // split 2+2 chains per gate: a (seeded) and b (zero), add at end
                f32x4 a0 = cvt4(sd[s & 1][0]);
                f32x4 a1 = cvt4(sd[s & 1][1]);
                f32x4 a2 = cvt4(sd[s & 1][2]);
                f32x4 a3 = cvt4(sd[s & 1][3]);
                f32x4 b0v = {0,0,0,0}, b1v = {0,0,0,0}, b2v = {0,0,0,0}, b3v = {0,0,0,0};
                if (s + 2 < 8) {
                    #pragma unroll
                    for (int gt = 0; gt < 4; ++gt)
                        sd[s & 1][gt] = ld8(sb + (size_t)((s + 2) * 4 + gt) * 2048);
                }
                a0 = MFMA16(whh[0][0], hf[0], a0);  a0 = MFMA16(whh[0][1], hf[1], a0);
                a1 = MFMA16(whh[1][0], hf[0], a1);  a1 = MFMA16(whh[1][1], hf[1], a1);
                a2 = MFMA16(whh[2][0], hf[0], a2);  a2 = MFMA16(whh[2][1], hf[1], a2);
                a3 = MFMA16(whh[3][0], hf[0], a3);  a3 = MFMA16(whh[3][1], hf[1], a3);
                b0v = MFMA16(whh[0][2], hf[2], b0v); b0v = MFMA16(whh[0][3], hf[3], b0v);
                b1v = MFMA16(whh[1][2], hf[2], b1v); b1v = MFMA16(whh[1][3], hf[3], b1v);
                b2v = MFMA16(whh[2][2], hf[2], b2v); b2v = MFMA16(whh[2][3], hf[3], b2v);
                b3v = MFMA16(whh[3][2], hf[2], b3v); b3v = MFMA16(whh[3][3], hf[3], b3v);
                a0 += b0v; a1 += b1v; a2 += b2v; a3 += b3v;

                half4_ h4;
                #pragma unroll
                for (int r = 0; r < 4; ++r) {
                    const float is  = sigm_(a0[r]);
                    const float fs  = sigm_(a1[r]);
                    const float gt_ = tanh_(a2[r]);
                    const float os  = sigm_(a3[r]);
                    cst[r] = fs * cst[r] + is * gt_;
                    h4[r] = (_Float16)(os * tanh_(cst[r]));
                }
                const int u0 = w * 16 + g * 4;
                *(half4_*)&hbuf[wr][cl][u0] = h4;
                st8(hb + (s * 16 + cl) * 128 + u0, h4);   // coherent h0 store

                if (s == 5 && tid == 0 && c + 1 < NCH) {
                    fwait(&fg0[bg], c + 2);
                    if (c + 1 >= RH) fwait(&fp1[bg], (c + 1) - (RH - 1));
                }

                if (s < 7) {
                    lds_barrier();
                } else {
                    __syncthreads();            // drains h0 stores + seed loads
                    if (tid == 0) {
                        frel(&fh0[bg], c + 1);  // h0 ready for P1
                        frel(&fs0[bg], c + 1);  // seeds0 slot free for P0
                    }
                }
            }
        }
    } else if (role == 2) {
        // ====================== P1: layer-1 input projection ======================
        half8 wf[4][4];
        #pragma unroll
        for (int gt = 0; gt < 4; ++gt) {
            const int grow = gt * 128 + w * 16 + cl;
            #pragma unroll
            for (int kt = 0; kt < 4; ++kt) {
                const float* pa = Wih1 + grow * H_ + kt * 32 + g * 8;
                f32x4 a0 = *(const f32x4*)(pa);
                f32x4 a1 = *(const f32x4*)(pa + 4);
                half8 fa;
                #pragma unroll
                for (int e = 0; e < 4; ++e) { fa[e] = (_Float16)a0[e]; fa[e + 4] = (_Float16)a1[e]; }
                wf[gt][kt] = fa;
            }
        }
        f32x4 bias[4];
        #pragma unroll
        for (int gt = 0; gt < 4; ++gt)
            #pragma unroll
            for (int r = 0; r < 4; ++r) {
                const int R = gt * 128 + w * 16 + g * 4 + r;
                bias[gt][r] = bih1[R] + bhh1[R];
            }
        const int pq_   = tid >> 2;
        const int sb_   = pq_ >> 3;
        const int strow = pq_ & 7;
        const int su0   = (tid & 3) * 32;
        __syncthreads();

        for (int c = 0; c < NCH; ++c) {
            if (tid == 0) {
                fwait(&fh0[bg], c + 1);                       // h0(c) ready
                if (c >= RS) fwait(&fs1[bg], c - (RS - 1));   // seeds1 slot free
            }
            __syncthreads();

            {   // stage h0 slot c -> xbuf via coherent ld8
                const _Float16* src = h0r + (size_t)(bg * RH + (c & (RH - 1))) * H0SLOT
                                    + (strow * 16 + sb_) * 128 + su0;
                #pragma unroll
                for (int e = 0; e < 8; ++e) {
                    half4_ v = ld8(src + e * 4);
                    *(half4_*)&xbuf[strow][sb_][su0 + e * 4] = v;
                }
            }
            lds_barrier();              // ds_writes done => src loads retired
            if (tid == 0) frel(&fp1[bg], c + 1);   // h0 slot free for S0

            _Float16* sbm = seeds1 + (size_t)(bg * RS + (c & (RS - 1))) * SEEDSLOT;
            for (int s = 0; s < 8; ++s) {
                half8 xf[4];
                #pragma unroll
                for (int kt = 0; kt < 4; ++kt)
                    xf[kt] = *(const half8*)&xbuf[s][cl][kt * 32 + g * 8];
                #pragma unroll
                for (int gt = 0; gt < 4; ++gt) {
                    f32x4 acc = bias[gt];
                    #pragma unroll
                    for (int kt = 0; kt < 4; ++kt)
                        acc = MFMA16(wf[gt][kt], xf[kt], acc);
                    st8(sbm + ((size_t)(s * 4 + gt) * 512 + tid) * 4, cvh4(acc));
                }
            }
            __syncthreads();                 // drains seeds1 stores + xbuf reads
            if (tid == 0) frel(&fg1[bg], c + 1);
        }
    } else {
        // ============ S1: light layer-1 recurrence + head ============
        half8 whh[4][4];
        #pragma unroll
        for (int gt = 0; gt < 4; ++gt) {
            const int grow = gt * 128 + w * 16 + cl;
            #pragma unroll
            for (int kt = 0; kt < 4; ++kt) {
                const float* pb = Whh1 + grow * H_ + kt * 32 + g * 8;
                f32x4 c0 = *(const f32x4*)(pb);
                f32x4 c1 = *(const f32x4*)(pb + 4);
                half8 fb;
                #pragma unroll
                for (int e = 0; e < 4; ++e) { fb[e] = (_Float16)c0[e]; fb[e + 4] = (_Float16)c1[e]; }
                whh[gt][kt] = fb;
            }
        }
        half8 waf[4];
        f32x4 ba4  = {0.f, 0.f, 0.f, 0.f};
        f32x4 oacc = {0.f, 0.f, 0.f, 0.f};
        #pragma unroll
        for (int kt = 0; kt < 4; ++kt) {
            const float* p = Wa + (w * 16 + cl) * H_ + kt * 32 + g * 8;
            f32x4 a0 = *(const f32x4*)(p);
            f32x4 a1 = *(const f32x4*)(p + 4);
            half8 f;
            #pragma unroll
            for (int e = 0; e < 4; ++e) { f[e] = (_Float16)a0[e]; f[e + 4] = (_Float16)a1[e]; }
            waf[kt] = f;
        }
        #pragma unroll
        for (int r = 0; r < 4; ++r) ba4[r] = ba[w * 16 + g * 4 + r];

        float cst[4] = {0.f, 0.f, 0.f, 0.f};
        half4_ sdn[2][4];
        __syncthreads();

        for (int c = 0; c < NCH; ++c) {
            const _Float16* sb = seeds1 + (size_t)(bg * RS + (c & (RS - 1))) * SEEDSLOT
                               + (size_t)tid * 4;
            half4_ sd[2][4];
            if (c == 0) {
                if (tid == 0) fwait(&fg1[bg], 1);
                __syncthreads();
                #pragma unroll
                for (int gt = 0; gt < 4; ++gt)
                    sd[0][gt] = ld8(sb + (size_t)(0 * 4 + gt) * 2048);
                #pragma unroll
                for (int gt = 0; gt < 4; ++gt)
                    sd[1][gt] = ld8(sb + (size_t)(1 * 4 + gt) * 2048);
            } else {
                #pragma unroll
                for (int gt = 0; gt < 4; ++gt) { sd[0][gt] = sdn[0][gt]; sd[1][gt] = sdn[1][gt]; }
            }

            #pragma unroll
            for (int s = 0; s < 8; ++s) {
                const int t  = c * 8 + s;
                const int rd = (s ^ 1) & 1;
                const int wr = s & 1;

                if (s == 6 && c + 1 < NCH) {    // cross-chunk seed prefetch
                    const _Float16* sbn = seeds1
                        + (size_t)(bg * RS + ((c + 1) & (RS - 1))) * SEEDSLOT
                        + (size_t)tid * 4;
                    #pragma unroll
                    for (int gt = 0; gt < 4; ++gt)
                        sdn[0][gt] = ld8(sbn + (size_t)(0 * 4 + gt) * 2048);
                    #pragma unroll
                    for (int gt = 0; gt < 4; ++gt)
                        sdn[1][gt] = ld8(sbn + (size_t)(1 * 4 + gt) * 2048);
                }

                half8 hf[4];       // h1(t-1)
                #pragma unroll
                for (int kt = 0; kt < 4; ++kt)
                    hf[kt] = *(const half8*)&hbuf[rd][cl][kt * 32 + g * 8];

                // split 2+2 chains + interleaved head chain (independent)
                f32x4 a0 = cvt4(sd[s & 1][0]);
                f32x4 a1 = cvt4(sd[s & 1][1]);
                f32x4 a2 = cvt4(sd[s & 1][2]);
                f32x4 a3 = cvt4(sd[s & 1][3]);
                f32x4 b0v = {0,0,0,0}, b1v = {0,0,0,0}, b2v = {0,0,0,0}, b3v = {0,0,0,0};
                f32x4 aacc = ba4;
                if (s + 2 < 8) {
                    #pragma unroll
                    for (int gt = 0; gt < 4; ++gt)
                        sd[s & 1][gt] = ld8(sb + (size_t)((s + 2) * 4 + gt) * 2048);
                }
                a0 = MFMA16(whh[0][0], hf[0], a0);  a0 = MFMA16(whh[0][1], hf[1], a0);
                a1 = MFMA16(whh[1][0], hf[0], a1);  a1 = MFMA16(whh[1][1], hf[1], a1);
                aacc = MFMA16(waf[0], hf[0], aacc);
                a2 = MFMA16(whh[2][0], hf[0], a2);  a2 = MFMA16(whh[2][1], hf[1], a2);
                a3 = MFMA16(whh[3][0], hf[0], a3);  a3 = MFMA16(whh[3][1], hf[1], a3);
                aacc = MFMA16(waf[1], hf[1], aacc);
                b0v = MFMA16(whh[0][2], hf[2], b0v); b0v = MFMA16(whh[0][3], hf[3], b0v);
                b1v = MFMA16(whh[1][2], hf[2], b1v); b1v = MFMA16(whh[1][3], hf[3], b1v);
                aacc = MFMA16(waf[2], hf[2], aacc);
                b2v = MFMA16(whh[2][2], hf[2], b2v); b2v = MFMA16(whh[2][3], hf[3], b2v);
                b3v = MFMA16(whh[3][2], hf[2], b3v); b3v = MFMA16(whh[3][3], hf[3], b3v);
                aacc = MFMA16(waf[3], hf[3], aacc);
                a0 += b0v; a1 += b1v; a2 += b2v; a3 += b3v;

                if (t > 0) {     // head term for h1(t-1)
                    #pragma unroll
                    for (int r = 0; r < 4; ++r) {
                        const float a = aacc[r];
                        oacc[r] += a * fmaxf(a, 0.f);
                    }
                }

                half4_ h4;
                #pragma unroll
                for (int r = 0; r < 4; ++r) {
                    const float is  = sigm_(a0[r]);
                    const float fs  = sigm_(a1[r]);
                    const float gt_ = tanh_(a2[r]);
                    const float os  = sigm_(a3[r]);
                    cst[r] = fs * cst[r] + is * gt_;
                    h4[r] = (_Float16)(os * tanh_(cst[r]));
                }
                const int u0 = w * 16 + g * 4;
                *(half4_*)&hbuf[wr][cl][u0] = h4;

                if (s == 5 && tid == 0 && c + 1 < NCH) fwait(&fg1[bg], c + 2);

                if (s < 7) {
                    lds_barrier();
                } else {
                    __syncthreads();               // seeds1 reads retired
                    if (tid == 0) frel(&fs1[bg], c + 1);
                }
            }
        }

        // final head term for h1(T-1) in hbuf[1]
        f32x4 aacc = ba4;
        #pragma unroll
        for (int kt = 0; kt < 4; ++kt) {
            const half8 hfv = *(const half8*)&hbuf[1][cl][kt * 32 + g * 8];
            aacc = MFMA16(waf[kt], hfv, aacc);
        }
        #pragma unroll
        for (int r = 0; r < 4; ++r) {
            const float a = aacc[r];
            oacc[r] += a * fmaxf(a, 0.f);
        }
        *(f32x4*)&out[(size_t)(b0 + cl) * H_ + w * 16 + g * 4] = oacc;
    }
}

extern "C" void kernel_launch(void* const* d_in, const int* in_sizes, int n_in,
                              void* d_out, int out_size, void* d_ws, size_t ws_size,
                              hipStream_t stream) {
    const float* y    = (const float*)d_in[0];
    const float* Wih0 = (const float*)d_in[1];
    const float* Whh0 = (const float*)d_in[2];
    const float* bih0 = (const float*)d_in[3];
    const float* bhh0 = (const float*)d_in[4];
    const float* Wih1 = (const float*)d_in[5];
    const float* Whh1 = (const float*)d_in[6];
    const float* bih1 = (const float*)d_in[7];
    const float* bhh1 = (const float*)d_in[8];
    const float* Wa   = (const float*)d_in[9];
    const float* ba   = (const float*)d_in[10];
    float* out = (float*)d_out;

    const size_t SEED_BYTES = (size_t)NBG * RS * SEEDSLOT * 2;   // 16 MiB each
    const size_t H0_BYTES   = (size_t)NBG * RH * H0SLOT * 2;     // 4 MiB
    char* p = (char*)d_ws;
    _Float16* seeds0 = (_Float16*)p;            p += SEED_BYTES;
    _Float16* seeds1 = (_Float16*)p;            p += SEED_BYTES;
    _Float16* h0r    = (_Float16*)p;            p += H0_BYTES;
    int*      flags  = (int*)p;

    hipMemsetAsync(flags, 0, 1024, stream);
    lstm4<<<4 * NBG, 512, 0, stream>>>(y, Wih0, Whh0, bih0, bhh0,
                                       Wih1, Whh1, bih1, bhh1, Wa, ba,
                                       seeds0, seeds1, h0r, flags, out);
}

// Round 22
// 535.104 us; speedup vs baseline: 1.0532x; 1.0532x over previous
//
#include <hip/hip_runtime.h>

// LSTMFeatureExtractor: 2-layer LSTM (H=128) over B=512, T=512, + a*relu(a) head.
// FINAL = Round 20 (session best: 534us total, kernel ~568us; baseline 1240us).
// 4-role pipeline, 128 blocks x 512 thr:
//  P0: seeds0 = bias0 + x@Wih0^T -> 4-deep ring (coherent st8, per-thread order)
//  S0: light rec-0 (16 hh-MFMAs, reg-prefetched seeds, cross-chunk prefetch),
//      h -> h0 ring via coherent st8. Credit for h0 slots comes from P1 staging.
//  P1: stage h0(c) (coherent ld8) -> release slot -> seeds1 = bias1 + Wih1*h0
//      -> ring (coherent st8).
//  S1: light rec-1 + head: 16 hh + 4 head MFMAs, reg-prefetched seeds1,
//      cross-chunk prefetch, nonlin, a*relu(a) -> out.
// Mechanics: relaxed agent atomics for all ring data (sc0sc1, coherent L3 --
// no per-chunk buffer_inv/wbl2), relaxed fetch_max flags after vmcnt-draining
// barriers (r18); chunk prologues hidden via s==5 pre-wait + s==6 register
// prefetch (r19). Rings depth 4. DAG: S0(c)<-{P0(c),P1(c-4)};
// P1(c)<-{S0(c),S1(c-4)}; S1(c)<-P1(c); P0(c)<-S0(c-4).
// r21's hand-scheduled 2+2 MFMA chain split REGRESSED (+5%) -- keep compiler
// scheduling for register-only code.

typedef _Float16 half8  __attribute__((ext_vector_type(8)));
typedef _Float16 half4_ __attribute__((ext_vector_type(4)));
typedef float    f32x4  __attribute__((ext_vector_type(4)));

#define H_    128
#define T_    512
#define B_    512
#define BCH   16
#define NBG   32
#define NCH   64                  // 8-step chunks
#define KPAD  136
#define RS    4                   // all ring depths
#define RH    4
#define SEEDSLOT (8 * 4 * 512 * 4)    // halves per (bg,slot): 65536 (128KB)
#define H0SLOT   (8 * 16 * 128)       // halves per (bg,slot): 16384 (32KB)

#define LOG2E 1.44269504089f

__device__ __forceinline__ float sigm_(float x) {
    return __builtin_amdgcn_rcpf(1.f + __builtin_amdgcn_exp2f(-LOG2E * x));
}
__device__ __forceinline__ float tanh_(float x) {
    return 1.f - 2.f * __builtin_amdgcn_rcpf(1.f + __builtin_amdgcn_exp2f((2.f * LOG2E) * x));
}
__device__ __forceinline__ void lds_barrier() {
    __builtin_amdgcn_sched_barrier(0);
    asm volatile("s_waitcnt lgkmcnt(0)" ::: "memory");
    __builtin_amdgcn_sched_barrier(0);
    __builtin_amdgcn_s_barrier();
    __builtin_amdgcn_sched_barrier(0);
}
__device__ __forceinline__ void fwait(const int* p, int tgt) {
    while (__hip_atomic_load(p, __ATOMIC_RELAXED, __HIP_MEMORY_SCOPE_AGENT) < tgt)
        __builtin_amdgcn_s_sleep(2);
}
__device__ __forceinline__ void frel(int* p, int v) {
    __hip_atomic_fetch_max(p, v, __ATOMIC_RELAXED, __HIP_MEMORY_SCOPE_AGENT);
}
__device__ __forceinline__ void st8(_Float16* p, half4_ v) {
    unsigned long long u;
    __builtin_memcpy(&u, &v, 8);
    __hip_atomic_store((unsigned long long*)p, u, __ATOMIC_RELAXED,
                       __HIP_MEMORY_SCOPE_AGENT);
}
__device__ __forceinline__ half4_ ld8(const _Float16* p) {
    unsigned long long u =
        __hip_atomic_load((const unsigned long long*)p, __ATOMIC_RELAXED,
                          __HIP_MEMORY_SCOPE_AGENT);
    half4_ v;
    __builtin_memcpy(&v, &u, 8);
    return v;
}
__device__ __forceinline__ f32x4 cvt4(half4_ h) {
    return f32x4{(float)h[0], (float)h[1], (float)h[2], (float)h[3]};
}
__device__ __forceinline__ half4_ cvh4(f32x4 v) {
    return half4_{(_Float16)v[0], (_Float16)v[1], (_Float16)v[2], (_Float16)v[3]};
}

#define MFMA16(A, Bv, C) __builtin_amdgcn_mfma_f32_16x16x32_f16((A), (Bv), (C), 0, 0, 0)

__global__ void __launch_bounds__(512)
lstm4(const float* __restrict__ y,
      const float* __restrict__ Wih0, const float* __restrict__ Whh0,
      const float* __restrict__ bih0, const float* __restrict__ bhh0,
      const float* __restrict__ Wih1, const float* __restrict__ Whh1,
      const float* __restrict__ bih1, const float* __restrict__ bhh1,
      const float* __restrict__ Wa,  const float* __restrict__ ba,
      _Float16* __restrict__ seeds0, _Float16* __restrict__ seeds1,
      _Float16* __restrict__ h0r,
      int* __restrict__ flags, float* __restrict__ out)
{
    __shared__ _Float16 xbuf[8][16][KPAD];   // P0/P1 staging
    __shared__ _Float16 hbuf[2][16][KPAD];   // S0/S1 h state

    const int tid = threadIdx.x;
    const int w   = tid >> 6;
    const int l   = tid & 63;
    const int g   = l >> 4;
    const int cl  = l & 15;
    const int role = blockIdx.x & 3;     // 0=P0 1=S0 2=P1 3=S1
    const int bg   = blockIdx.x >> 2;
    const int b0   = bg * BCH;

    int* fg0 = flags;         // P0 -> S0: seeds0 ready
    int* fs0 = flags + 32;    // S0 -> P0: seeds0 slot credit
    int* fh0 = flags + 64;    // S0 -> P1: h0 chunk ready
    int* fp1 = flags + 96;    // P1 -> S0: h0 slot credit (after staging)
    int* fg1 = flags + 128;   // P1 -> S1: seeds1 ready
    int* fs1 = flags + 160;   // S1 -> P1: seeds1 slot credit

    { // zero hbuf (initial h state for S roles)
        int* q = (int*)&hbuf[0][0][0];
        for (int i = tid; i < (int)(sizeof(hbuf) / 4); i += 512) q[i] = 0;
    }

    if (role == 0) {
        // ====================== P0: layer-0 input projection ======================
        half8 wf[4][4];
        #pragma unroll
        for (int gt = 0; gt < 4; ++gt) {
            const int grow = gt * 128 + w * 16 + cl;
            #pragma unroll
            for (int kt = 0; kt < 4; ++kt) {
                const float* pa = Wih0 + grow * H_ + kt * 32 + g * 8;
                f32x4 a0 = *(const f32x4*)(pa);
                f32x4 a1 = *(const f32x4*)(pa + 4);
                half8 fa;
                #pragma unroll
                for (int e = 0; e < 4; ++e) { fa[e] = (_Float16)a0[e]; fa[e + 4] = (_Float16)a1[e]; }
                wf[gt][kt] = fa;
            }
        }
        f32x4 bias[4];
        #pragma unroll
        for (int gt = 0; gt < 4; ++gt)
            #pragma unroll
            for (int r = 0; r < 4; ++r) {
                const int R = gt * 128 + w * 16 + g * 4 + r;
                bias[gt][r] = bih0[R] + bhh0[R];
            }
        __syncthreads();

        for (int c = 0; c < NCH; ++c) {
            if (tid == 0 && c >= RS) fwait(&fs0[bg], c - (RS - 1));
            __syncthreads();

            // stage y[b][k][c*8..+8) -> xbuf (f16)
            #pragma unroll
            for (int rr = 0; rr < 4; ++rr) {
                const int q = tid + rr * 512;
                const int b = q >> 7, k = q & 127;
                const float* src = y + ((size_t)((b0 + b) * H_ + k)) * T_ + c * 8;
                f32x4 v0 = *(const f32x4*)(src);
                f32x4 v1 = *(const f32x4*)(src + 4);
                #pragma unroll
                for (int e = 0; e < 4; ++e) {
                    xbuf[e][b][k]     = (_Float16)v0[e];
                    xbuf[e + 4][b][k] = (_Float16)v1[e];
                }
            }
            lds_barrier();

            _Float16* sb = seeds0 + (size_t)(bg * RS + (c & (RS - 1))) * SEEDSLOT;
            for (int s = 0; s < 8; ++s) {
                half8 xf[4];
                #pragma unroll
                for (int kt = 0; kt < 4; ++kt)
                    xf[kt] = *(const half8*)&xbuf[s][cl][kt * 32 + g * 8];
                #pragma unroll
                for (int gt = 0; gt < 4; ++gt) {
                    f32x4 acc = bias[gt];
                    #pragma unroll
                    for (int kt = 0; kt < 4; ++kt)
                        acc = MFMA16(wf[gt][kt], xf[kt], acc);
                    st8(sb + ((size_t)(s * 4 + gt) * 512 + tid) * 4, cvh4(acc));
                }
            }
            __syncthreads();                 // drains sc0sc1 stores (vmcnt)
            if (tid == 0) frel(&fg0[bg], c + 1);
        }
    } else if (role == 1) {
        // ====================== S0: light recurrence, layer 0 ======================
        half8 whh[4][4];
        #pragma unroll
        for (int gt = 0; gt < 4; ++gt) {
            const int grow = gt * 128 + w * 16 + cl;
            #pragma unroll
            for (int kt = 0; kt < 4; ++kt) {
                const float* pb = Whh0 + grow * H_ + kt * 32 + g * 8;
                f32x4 c0 = *(const f32x4*)(pb);
                f32x4 c1 = *(const f32x4*)(pb + 4);
                half8 fb;
                #pragma unroll
                for (int e = 0; e < 4; ++e) { fb[e] = (_Float16)c0[e]; fb[e + 4] = (_Float16)c1[e]; }
                whh[gt][kt] = fb;
            }
        }
        float cst[4] = {0.f, 0.f, 0.f, 0.f};
        half4_ sdn[2][4];
        __syncthreads();

        for (int c = 0; c < NCH; ++c) {
            const _Float16* sb = seeds0 + (size_t)(bg * RS + (c & (RS - 1))) * SEEDSLOT
                               + (size_t)tid * 4;
            _Float16* hb = h0r + (size_t)(bg * RH + (c & (RH - 1))) * H0SLOT;

            half4_ sd[2][4];
            if (c == 0) {
                if (tid == 0) fwait(&fg0[bg], 1);
                __syncthreads();
                #pragma unroll
                for (int gt = 0; gt < 4; ++gt)
                    sd[0][gt] = ld8(sb + (size_t)(0 * 4 + gt) * 2048);
                #pragma unroll
                for (int gt = 0; gt < 4; ++gt)
                    sd[1][gt] = ld8(sb + (size_t)(1 * 4 + gt) * 2048);
            } else {
                #pragma unroll
                for (int gt = 0; gt < 4; ++gt) { sd[0][gt] = sdn[0][gt]; sd[1][gt] = sdn[1][gt]; }
            }

            #pragma unroll
            for (int s = 0; s < 8; ++s) {
                const int rd = (s ^ 1) & 1;
                const int wr = s & 1;

                if (s == 6 && c + 1 < NCH) {    // cross-chunk seed prefetch
                    const _Float16* sbn = seeds0
                        + (size_t)(bg * RS + ((c + 1) & (RS - 1))) * SEEDSLOT
                        + (size_t)tid * 4;
                    #pragma unroll
                    for (int gt = 0; gt < 4; ++gt)
                        sdn[0][gt] = ld8(sbn + (size_t)(0 * 4 + gt) * 2048);
                    #pragma unroll
                    for (int gt = 0; gt < 4; ++gt)
                        sdn[1][gt] = ld8(sbn + (size_t)(1 * 4 + gt) * 2048);
                }

                half8 hf[4];
                #pragma unroll
                for (int kt = 0; kt < 4; ++kt)
                    hf[kt] = *(const half8*)&hbuf[rd][cl][kt * 32 + g * 8];

                f32x4 a0 = cvt4(sd[s & 1][0]);
                f32x4 a1 = cvt4(sd[s & 1][1]);
                f32x4 a2 = cvt4(sd[s & 1][2]);
                f32x4 a3 = cvt4(sd[s & 1][3]);
                if (s + 2 < 8) {
                    #pragma unroll
                    for (int gt = 0; gt < 4; ++gt)
                        sd[s & 1][gt] = ld8(sb + (size_t)((s + 2) * 4 + gt) * 2048);
                }

                #pragma unroll
                for (int kt = 0; kt < 4; ++kt) {
                    a0 = MFMA16(whh[0][kt], hf[kt], a0);
                    a1 = MFMA16(whh[1][kt], hf[kt], a1);
                    a2 = MFMA16(whh[2][kt], hf[kt], a2);
                    a3 = MFMA16(whh[3][kt], hf[kt], a3);
                }

                half4_ h4;
                #pragma unroll
                for (int r = 0; r < 4; ++r) {
                    const float is  = sigm_(a0[r]);
                    const float fs  = sigm_(a1[r]);
                    const float gt_ = tanh_(a2[r]);
                    const float os  = sigm_(a3[r]);
                    cst[r] = fs * cst[r] + is * gt_;
                    h4[r] = (_Float16)(os * tanh_(cst[r]));
                }
                const int u0 = w * 16 + g * 4;
                *(half4_*)&hbuf[wr][cl][u0] = h4;
                st8(hb + (s * 16 + cl) * 128 + u0, h4);   // coherent h0 store

                // pre-wait next chunk's flags (off-chain; propagated by barrier)
                if (s == 5 && tid == 0 && c + 1 < NCH) {
                    fwait(&fg0[bg], c + 2);
                    if (c + 1 >= RH) fwait(&fp1[bg], (c + 1) - (RH - 1));
                }

                if (s < 7) {
                    lds_barrier();
                } else {
                    __syncthreads();            // drains h0 stores + seed loads
                    if (tid == 0) {
                        frel(&fh0[bg], c + 1);  // h0 ready for P1
                        frel(&fs0[bg], c + 1);  // seeds0 slot free for P0
                    }
                }
            }
        }
    } else if (role == 2) {
        // ====================== P1: layer-1 input projection ======================
        half8 wf[4][4];
        #pragma unroll
        for (int gt = 0; gt < 4; ++gt) {
            const int grow = gt * 128 + w * 16 + cl;
            #pragma unroll
            for (int kt = 0; kt < 4; ++kt) {
                const float* pa = Wih1 + grow * H_ + kt * 32 + g * 8;
                f32x4 a0 = *(const f32x4*)(pa);
                f32x4 a1 = *(const f32x4*)(pa + 4);
                half8 fa;
                #pragma unroll
                for (int e = 0; e < 4; ++e) { fa[e] = (_Float16)a0[e]; fa[e + 4] = (_Float16)a1[e]; }
                wf[gt][kt] = fa;
            }
        }
        f32x4 bias[4];
        #pragma unroll
        for (int gt = 0; gt < 4; ++gt)
            #pragma unroll
            for (int r = 0; r < 4; ++r) {
                const int R = gt * 128 + w * 16 + g * 4 + r;
                bias[gt][r] = bih1[R] + bhh1[R];
            }
        // staging thread geometry (per-thread-contiguous 64B)
        const int pq_   = tid >> 2;
        const int sb_   = pq_ >> 3;
        const int strow = pq_ & 7;
        const int su0   = (tid & 3) * 32;
        __syncthreads();

        for (int c = 0; c < NCH; ++c) {
            if (tid == 0) {
                fwait(&fh0[bg], c + 1);                       // h0(c) ready
                if (c >= RS) fwait(&fs1[bg], c - (RS - 1));   // seeds1 slot free
            }
            __syncthreads();

            {   // stage h0 slot c -> xbuf via coherent ld8
                const _Float16* src = h0r + (size_t)(bg * RH + (c & (RH - 1))) * H0SLOT
                                    + (strow * 16 + sb_) * 128 + su0;
                #pragma unroll
                for (int e = 0; e < 8; ++e) {
                    half4_ v = ld8(src + e * 4);
                    *(half4_*)&xbuf[strow][sb_][su0 + e * 4] = v;
                }
            }
            lds_barrier();              // ds_writes done => src loads retired
            if (tid == 0) frel(&fp1[bg], c + 1);   // h0 slot free for S0

            _Float16* sbm = seeds1 + (size_t)(bg * RS + (c & (RS - 1))) * SEEDSLOT;
            for (int s = 0; s < 8; ++s) {
                half8 xf[4];
                #pragma unroll
                for (int kt = 0; kt < 4; ++kt)
                    xf[kt] = *(const half8*)&xbuf[s][cl][kt * 32 + g * 8];
                #pragma unroll
                for (int gt = 0; gt < 4; ++gt) {
                    f32x4 acc = bias[gt];
                    #pragma unroll
                    for (int kt = 0; kt < 4; ++kt)
                        acc = MFMA16(wf[gt][kt], xf[kt], acc);
                    st8(sbm + ((size_t)(s * 4 + gt) * 512 + tid) * 4, cvh4(acc));
                }
            }
            __syncthreads();                 // drains seeds1 stores + xbuf reads
            if (tid == 0) frel(&fg1[bg], c + 1);
        }
    } else {
        // ============ S1: light layer-1 recurrence + head ============
        half8 whh[4][4];
        #pragma unroll
        for (int gt = 0; gt < 4; ++gt) {
            const int grow = gt * 128 + w * 16 + cl;
            #pragma unroll
            for (int kt = 0; kt < 4; ++kt) {
                const float* pb = Whh1 + grow * H_ + kt * 32 + g * 8;
                f32x4 c0 = *(const f32x4*)(pb);
                f32x4 c1 = *(const f32x4*)(pb + 4);
                half8 fb;
                #pragma unroll
                for (int e = 0; e < 4; ++e) { fb[e] = (_Float16)c0[e]; fb[e + 4] = (_Float16)c1[e]; }
                whh[gt][kt] = fb;
            }
        }
        half8 waf[4];
        f32x4 ba4  = {0.f, 0.f, 0.f, 0.f};
        f32x4 oacc = {0.f, 0.f, 0.f, 0.f};
        #pragma unroll
        for (int kt = 0; kt < 4; ++kt) {
            const float* p = Wa + (w * 16 + cl) * H_ + kt * 32 + g * 8;
            f32x4 a0 = *(const f32x4*)(p);
            f32x4 a1 = *(const f32x4*)(p + 4);
            half8 f;
            #pragma unroll
            for (int e = 0; e < 4; ++e) { f[e] = (_Float16)a0[e]; f[e + 4] = (_Float16)a1[e]; }
            waf[kt] = f;
        }
        #pragma unroll
        for (int r = 0; r < 4; ++r) ba4[r] = ba[w * 16 + g * 4 + r];

        float cst[4] = {0.f, 0.f, 0.f, 0.f};
        half4_ sdn[2][4];
        __syncthreads();

        for (int c = 0; c < NCH; ++c) {
            const _Float16* sb = seeds1 + (size_t)(bg * RS + (c & (RS - 1))) * SEEDSLOT
                               + (size_t)tid * 4;
            half4_ sd[2][4];
            if (c == 0) {
                if (tid == 0) fwait(&fg1[bg], 1);
                __syncthreads();
                #pragma unroll
                for (int gt = 0; gt < 4; ++gt)
                    sd[0][gt] = ld8(sb + (size_t)(0 * 4 + gt) * 2048);
                #pragma unroll
                for (int gt = 0; gt < 4; ++gt)
                    sd[1][gt] = ld8(sb + (size_t)(1 * 4 + gt) * 2048);
            } else {
                #pragma unroll
                for (int gt = 0; gt < 4; ++gt) { sd[0][gt] = sdn[0][gt]; sd[1][gt] = sdn[1][gt]; }
            }

            #pragma unroll
            for (int s = 0; s < 8; ++s) {
                const int t  = c * 8 + s;
                const int rd = (s ^ 1) & 1;
                const int wr = s & 1;

                if (s == 6 && c + 1 < NCH) {    // cross-chunk seed prefetch
                    const _Float16* sbn = seeds1
                        + (size_t)(bg * RS + ((c + 1) & (RS - 1))) * SEEDSLOT
                        + (size_t)tid * 4;
                    #pragma unroll
                    for (int gt = 0; gt < 4; ++gt)
                        sdn[0][gt] = ld8(sbn + (size_t)(0 * 4 + gt) * 2048);
                    #pragma unroll
                    for (int gt = 0; gt < 4; ++gt)
                        sdn[1][gt] = ld8(sbn + (size_t)(1 * 4 + gt) * 2048);
                }

                half8 hf[4];       // h1(t-1)
                #pragma unroll
                for (int kt = 0; kt < 4; ++kt)
                    hf[kt] = *(const half8*)&hbuf[rd][cl][kt * 32 + g * 8];

                f32x4 a0 = cvt4(sd[s & 1][0]);
                f32x4 a1 = cvt4(sd[s & 1][1]);
                f32x4 a2 = cvt4(sd[s & 1][2]);
                f32x4 a3 = cvt4(sd[s & 1][3]);
                if (s + 2 < 8) {
                    #pragma unroll
                    for (int gt = 0; gt < 4; ++gt)
                        sd[s & 1][gt] = ld8(sb + (size_t)((s + 2) * 4 + gt) * 2048);
                }
                #pragma unroll
                for (int kt = 0; kt < 4; ++kt) {
                    a0 = MFMA16(whh[0][kt], hf[kt], a0);
                    a1 = MFMA16(whh[1][kt], hf[kt], a1);
                    a2 = MFMA16(whh[2][kt], hf[kt], a2);
                    a3 = MFMA16(whh[3][kt], hf[kt], a3);
                }

                if (t > 0) {     // head term for h1(t-1)
                    f32x4 aacc = ba4;
                    #pragma unroll
                    for (int kt = 0; kt < 4; ++kt) aacc = MFMA16(waf[kt], hf[kt], aacc);
                    #pragma unroll
                    for (int r = 0; r < 4; ++r) {
                        const float a = aacc[r];
                        oacc[r] += a * fmaxf(a, 0.f);
                    }
                }

                half4_ h4;
                #pragma unroll
                for (int r = 0; r < 4; ++r) {
                    const float is  = sigm_(a0[r]);
                    const float fs  = sigm_(a1[r]);
                    const float gt_ = tanh_(a2[r]);
                    const float os  = sigm_(a3[r]);
                    cst[r] = fs * cst[r] + is * gt_;
                    h4[r] = (_Float16)(os * tanh_(cst[r]));
                }
                const int u0 = w * 16 + g * 4;
                *(half4_*)&hbuf[wr][cl][u0] = h4;

                if (s == 5 && tid == 0 && c + 1 < NCH) fwait(&fg1[bg], c + 2);

                if (s < 7) {
                    lds_barrier();
                } else {
                    __syncthreads();               // seeds1 reads retired
                    if (tid == 0) frel(&fs1[bg], c + 1);
                }
            }
        }

        // final head term for h1(T-1) in hbuf[1]
        f32x4 aacc = ba4;
        #pragma unroll
        for (int kt = 0; kt < 4; ++kt) {
            const half8 hfv = *(const half8*)&hbuf[1][cl][kt * 32 + g * 8];
            aacc = MFMA16(waf[kt], hfv, aacc);
        }
        #pragma unroll
        for (int r = 0; r < 4; ++r) {
            const float a = aacc[r];
            oacc[r] += a * fmaxf(a, 0.f);
        }
        *(f32x4*)&out[(size_t)(b0 + cl) * H_ + w * 16 + g * 4] = oacc;
    }
}

extern "C" void kernel_launch(void* const* d_in, const int* in_sizes, int n_in,
                              void* d_out, int out_size, void* d_ws, size_t ws_size,
                              hipStream_t stream) {
    const float* y    = (const float*)d_in[0];
    const float* Wih0 = (const float*)d_in[1];
    const float* Whh0 = (const float*)d_in[2];
    const float* bih0 = (const float*)d_in[3];
    const float* bhh0 = (const float*)d_in[4];
    const float* Wih1 = (const float*)d_in[5];
    const float* Whh1 = (const float*)d_in[6];
    const float* bih1 = (const float*)d_in[7];
    const float* bhh1 = (const float*)d_in[8];
    const float* Wa   = (const float*)d_in[9];
    const float* ba   = (const float*)d_in[10];
    float* out = (float*)d_out;

    const size_t SEED_BYTES = (size_t)NBG * RS * SEEDSLOT * 2;   // 16 MiB each
    const size_t H0_BYTES   = (size_t)NBG * RH * H0SLOT * 2;     // 4 MiB
    char* p = (char*)d_ws;
    _Float16* seeds0 = (_Float16*)p;            p += SEED_BYTES;
    _Float16* seeds1 = (_Float16*)p;            p += SEED_BYTES;
    _Float16* h0r    = (_Float16*)p;            p += H0_BYTES;
    int*      flags  = (int*)p;

    hipMemsetAsync(flags, 0, 1024, stream);
    lstm4<<<4 * NBG, 512, 0, stream>>>(y, Wih0, Whh0, bih0, bhh0,
                                       Wih1, Whh1, bih1, bhh1, Wa, ba,
                                       seeds0, seeds1, h0r, flags, out);
}